// Round 6
// baseline (293.739 us; speedup 1.0000x reference)
//
#include <hip/hip_runtime.h>

// Problem constants (from reference): F=50000, K=32, E=128, N=100000
#define F_TOTAL 50000
#define KNBR    32
#define EMB     128
#define FB      16      // f-rows per block (3125 * 16 == 50000 exactly)
#define RPW     4       // rows per wave (4 waves * 4 = 16)
#define CHK     8       // neighbors per chunk

// Single fused kernel. Max-free softmax makes one pass possible:
//   alpha_k = embi[idx_k].u is bounded (|alpha| < ~6 for this data), so
//   w_k = exp(alpha_k) (exactly 0 for pad via ballot mask, matching the
//   reference's exp(-10000+..) underflow), acc += w_k * row_k (row still in
//   registers from the dot), normalize by s = sum w at the end. Chunks of 8
//   are fully INDEPENDENT (no online-rescale chain), double-buffered loads.
// Phase B: gate = sigmoid(cat @ W^T + b); out = g*embf + (1-g)*agg.
//   (unchanged from rounds 3-5: thread -> column pair, wave -> j-quarter,
//    W 128KB read once per block, LDS partial combine.)
__global__ __launch_bounds__(256, 4)
void fused_gnn(const int*   __restrict__ adj,    // [F,K] int32
               const float* __restrict__ embi,   // [N,E]
               const float* __restrict__ embf,   // [F,E]
               const float* __restrict__ u,      // [E,1]
               const float* __restrict__ W,      // [E,2E]
               const float* __restrict__ bias,   // [E]
               float*       __restrict__ out)    // [F,E]
{
    __shared__ float catbuf[FB][2 * EMB];  // 16 KB
    __shared__ float pbuf[FB][EMB];        //  8 KB

    const int tid   = threadIdx.x;
    const int wave  = tid >> 6;
    const int lane  = tid & 63;
    const int fbase = blockIdx.x * FB;

    // per-lane u values for columns 2*lane, 2*lane+1
    const float2 uv = *(const float2*)(u + 2 * lane);

    // ---------------- Phase A: one-pass attention ----------------
    for (int i = 0; i < RPW; ++i) {
        const int r = wave * RPW + i;
        const int f = fbase + r;

        // lane holds neighbor k = lane&31 (upper half duplicates)
        const int myidx = adj[f * KNBR + (lane & 31)];
        // pad mask bits for all 32 k's, one ballot per row
        const unsigned long long nz = __ballot(myidx != 0);

        // embf row load issued early, consumed at the staging write
        const float2 ef = *(const float2*)(embf + (size_t)f * EMB + 2 * lane);

        // prologue: chunk-0 gather (8 independent coalesced 512B loads)
        float2 nbA[CHK], nbB[CHK];
#pragma unroll
        for (int j = 0; j < CHK; ++j) {
            const unsigned ik = (unsigned)__builtin_amdgcn_readlane(myidx, j);
            nbA[j] = *(const float2*)(embi + (size_t)ik * EMB + 2 * lane);
        }

        float2 acc = make_float2(0.f, 0.f);   // unnormalized weighted sum
        float  se  = 0.f;                     // per-lane partial of denom

#pragma unroll
        for (int c = 0; c < KNBR / CHK; ++c) {
            float2* cur = (c & 1) ? nbB : nbA;   // folds to static after unroll
            float2* nxt = (c & 1) ? nbA : nbB;
            if (c < KNBR / CHK - 1) {
#pragma unroll
                for (int j = 0; j < CHK; ++j) {
                    const unsigned ik = (unsigned)__builtin_amdgcn_readlane(
                        myidx, (c + 1) * CHK + j);
                    nxt[j] = *(const float2*)(embi + (size_t)ik * EMB + 2 * lane);
                }
            }

            // per-lane partial dots with u
            float v[CHK];
#pragma unroll
            for (int j = 0; j < CHK; ++j)
                v[j] = cur[j].x * uv.x + cur[j].y * uv.y;

            // multi-value butterfly over bits 4,2,1: lane ends holding the
            // 8-lane-group partial for k_local = lane&7 (construction verified
            // in rounds 1/2)
#pragma unroll
            for (int bit = 4; bit >= 1; bit >>= 1) {
                const bool upper = (lane & bit) != 0;
#pragma unroll
                for (int j = 0; j < bit; ++j) {
                    const float send = upper ? v[j] : v[j + bit];
                    const float recv = __shfl_xor(send, bit);
                    v[j] = (upper ? v[j + bit] : v[j]) + recv;
                }
            }
            // fold remaining lane bits: full 64-lane dot for k = c*8 + (lane&7)
            float alpha = v[0];
            alpha += __shfl_xor(alpha, 8);
            alpha += __shfl_xor(alpha, 16);
            alpha += __shfl_xor(alpha, 32);

            // weight; pad -> exact 0 (reference: exp(-10000+..) underflows to 0)
            const int kg = c * CHK + (lane & 7);
            const float e = ((nz >> kg) & 1ull) ? __expf(alpha) : 0.0f;
            se += e;

            // unnormalized weighted accumulate, rows still register-resident;
            // lane j (j<8) holds e for k_local = j
#pragma unroll
            for (int j = 0; j < CHK; ++j) {
                const float w = __uint_as_float((unsigned)__builtin_amdgcn_readlane(
                    (int)__float_as_uint(e), j));
                acc.x = fmaf(w, cur[j].x, acc.x);
                acc.y = fmaf(w, cur[j].y, acc.y);
            }
        }

        // denom: e is uniform across the 8 lane-groups, so summing one
        // 8-lane group (bits 1,2,4) of se already gives s = sum_k e_k
        float S = se;
        S += __shfl_xor(S, 1);
        S += __shfl_xor(S, 2);
        S += __shfl_xor(S, 4);
        const float inv = 1.0f / S;
        acc.x *= inv;
        acc.y *= inv;

        // stage cat = [embf_row, agg] into LDS
        *(float2*)&catbuf[r][2 * lane]       = ef;
        *(float2*)&catbuf[r][EMB + 2 * lane] = acc;
    }
    __syncthreads();

    // ---------------- Phase B: gate GEMM + blend ----------------
    const int p  = tid & 63;
    const int g  = tid >> 6;       // == wave (divergence is wave-uniform)
    const int c0 = 2 * p, c1 = c0 + 1;
    const int jbase = g * 64;

    float acc0[FB], acc1[FB];
#pragma unroll
    for (int r = 0; r < FB; ++r) { acc0[r] = 0.f; acc1[r] = 0.f; }

    const float* W0 = W + (size_t)c0 * (2 * EMB) + jbase;
    const float* W1 = W + (size_t)c1 * (2 * EMB) + jbase;

#pragma unroll 4
    for (int j = 0; j < 64; j += 4) {
        const float4 w0 = *(const float4*)(W0 + j);
        const float4 w1 = *(const float4*)(W1 + j);
#pragma unroll
        for (int r = 0; r < FB; ++r) {
            const float4 cv = *(const float4*)&catbuf[r][jbase + j];  // broadcast
            acc0[r] += cv.x * w0.x + cv.y * w0.y + cv.z * w0.z + cv.w * w0.w;
            acc1[r] += cv.x * w1.x + cv.y * w1.y + cv.z * w1.z + cv.w * w1.w;
        }
    }

    // combine the 4 j-quarter partials via LDS (wave-serialized, cheap)
    if (g == 3) {
#pragma unroll
        for (int r = 0; r < FB; ++r) { pbuf[r][c0] = acc0[r]; pbuf[r][c1] = acc1[r]; }
    }
    __syncthreads();
    if (g == 2) {
#pragma unroll
        for (int r = 0; r < FB; ++r) { pbuf[r][c0] += acc0[r]; pbuf[r][c1] += acc1[r]; }
    }
    __syncthreads();
    if (g == 1) {
#pragma unroll
        for (int r = 0; r < FB; ++r) { pbuf[r][c0] += acc0[r]; pbuf[r][c1] += acc1[r]; }
    }
    __syncthreads();
    if (g == 0) {
        const float2 bv = *(const float2*)(bias + c0);
#pragma unroll
        for (int r = 0; r < FB; ++r) {
            const float t0 = acc0[r] + pbuf[r][c0] + bv.x;
            const float t1 = acc1[r] + pbuf[r][c1] + bv.y;
            const float g0 = 1.f / (1.f + __expf(-t0));
            const float g1 = 1.f / (1.f + __expf(-t1));
            const float e0 = catbuf[r][c0],       e1 = catbuf[r][c1];
            const float a0 = catbuf[r][EMB + c0], a1 = catbuf[r][EMB + c1];
            float2 o;
            o.x = g0 * e0 + (1.f - g0) * a0;
            o.y = g1 * e1 + (1.f - g1) * a1;
            *(float2*)(out + (size_t)(fbase + r) * EMB + c0) = o;
        }
    }
}

extern "C" void kernel_launch(void* const* d_in, const int* in_sizes, int n_in,
                              void* d_out, int out_size, void* d_ws, size_t ws_size,
                              hipStream_t stream) {
    const int*   adj  = (const int*)  d_in[0];  // adjacency_fi [F,K] int32
    const float* embi = (const float*)d_in[1];  // embedding_i [N,E]
    const float* embf = (const float*)d_in[2];  // embedding_f_weight [F,E]
    const float* u    = (const float*)d_in[3];  // u [E,1]
    const float* W    = (const float*)d_in[4];  // W_weight [E,2E]
    const float* bias = (const float*)d_in[5];  // W_bias [E]
    float* outp = (float*)d_out;

    // 50000 = 3125 * 16 exactly -> no tail guard needed; single fused kernel
    fused_gnn<<<F_TOTAL / FB, 256, 0, stream>>>(adj, embi, embf, u, W, bias, outp);
}

// Round 7
// 261.447 us; speedup vs baseline: 1.1235x; 1.1235x over previous
//
#include <hip/hip_runtime.h>

// Problem constants (from reference): F=50000, K=32, E=128, N=100000
#define F_TOTAL 50000
#define N_NODE  100000
#define KNBR    32
#define EMB     128
#define FB      16      // f-rows per block (3125 * 16 == 50000 exactly)
#define RPW     4       // rows per wave (4 waves * 4 = 16)

// ---------------------------------------------------------------------------
// Kernel 1: y[n] = embi[n] . u   (rank-1 score is f-independent)
// 8 rows per wave: 8 independent 512B loads, multi-value butterfly
// (bits 4,2,1) + xor 8/16/32 folds. 3125*4*8 = 100000 exactly.
// ---------------------------------------------------------------------------
__global__ __launch_bounds__(256)
void node_scores(const float* __restrict__ embi,
                 const float* __restrict__ u,
                 float*       __restrict__ y)
{
    const int wave = threadIdx.x >> 6;
    const int lane = threadIdx.x & 63;
    const float2 uv = *(const float2*)(u + 2 * lane);

    const int base = (blockIdx.x * 4 + wave) * 8;

    float v[8];
#pragma unroll
    for (int j = 0; j < 8; ++j) {
        const float2 e = *(const float2*)(embi + (size_t)(base + j) * EMB + 2 * lane);
        v[j] = e.x * uv.x + e.y * uv.y;
    }

#pragma unroll
    for (int bit = 4; bit >= 1; bit >>= 1) {
        const bool upper = (lane & bit) != 0;
#pragma unroll
        for (int j = 0; j < bit; ++j) {
            const float send = upper ? v[j] : v[j + bit];
            const float recv = __shfl_xor(send, bit);
            v[j] = (upper ? v[j + bit] : v[j]) + recv;
        }
    }
    float d = v[0];
    d += __shfl_xor(d, 8);
    d += __shfl_xor(d, 16);
    d += __shfl_xor(d, 32);   // full 64-lane sum for row base + (lane&7)

    if (lane < 8) y[base + lane] = d;
}

// ---------------------------------------------------------------------------
// Kernel 2: fused attention + gated fusion.
// Phase A per row: alpha = y[adj[f,k]] + mask (4B gather, y is L2-resident),
//   then ALL 32 neighbor-row loads are issued up front and PINNED above a
//   sched_barrier(0) so the scheduler cannot sink them to their uses
//   (round-5 lesson: without the barrier it rescheduled back to ~8 in
//   flight, VGPR=52). Softmax (10 shfl + exp) runs under the in-flight
//   loads; aggregate consumes nb[k] in issue order -> graduated vmcnt.
// Phase B: gate = sigmoid(cat @ W^T + b); out = g*embf + (1-g)*agg.
// ---------------------------------------------------------------------------
__global__ __launch_bounds__(256, 4)
void fused_gnn(const int*   __restrict__ adj,    // [F,K] int32
               const float* __restrict__ embi,   // [N,E]
               const float* __restrict__ embf,   // [F,E]
               const float* __restrict__ y,      // [N] precomputed scores
               const float* __restrict__ W,      // [E,2E]
               const float* __restrict__ bias,   // [E]
               float*       __restrict__ out)    // [F,E]
{
    __shared__ float catbuf[FB][2 * EMB];  // 16 KB
    __shared__ float pbuf[FB][EMB];        //  8 KB

    const int tid   = threadIdx.x;
    const int wave  = tid >> 6;
    const int lane  = tid & 63;
    const int fbase = blockIdx.x * FB;

    // ---------------- Phase A: attention ----------------
    for (int i = 0; i < RPW; ++i) {
        const int r = wave * RPW + i;
        const int f = fbase + r;

        const int myidx = adj[f * KNBR + (lane & 31)];

        // issue the score gather and the embf row load early
        const float yv = y[myidx];
        const float2 ef = *(const float2*)(embf + (size_t)f * EMB + 2 * lane);

        // issue ALL 32 neighbor-row loads (readlane -> uniform SGPR base,
        // 512B coalesced each), then pin them with a scheduling barrier.
        float2 nb[KNBR];
#pragma unroll
        for (int k = 0; k < KNBR; ++k) {
            const unsigned ik = (unsigned)__builtin_amdgcn_readlane(myidx, k);
            nb[k] = *(const float2*)(embi + (size_t)ik * EMB + 2 * lane);
        }
        __builtin_amdgcn_sched_barrier(0);   // loads may NOT sink below here

        // softmax over the 32 k's (runs while the 32 loads are in flight)
        float alpha = yv + ((myidx != 0) ? 0.0f : -10000.0f);
        float mx = alpha;
#pragma unroll
        for (int bit = 1; bit <= 16; bit <<= 1)
            mx = fmaxf(mx, __shfl_xor(mx, bit));
        const float e = __expf(alpha - mx);
        float s = e;
#pragma unroll
        for (int bit = 1; bit <= 16; bit <<= 1)
            s += __shfl_xor(s, bit);
        const float an = e / s;   // normalized weight for k = lane&31

        // aggregate: consume rows in issue order (graduated vmcnt waits)
        float2 acc = make_float2(0.f, 0.f);
#pragma unroll
        for (int k = 0; k < KNBR; ++k) {
            const float a = __uint_as_float((unsigned)__builtin_amdgcn_readlane(
                (int)__float_as_uint(an), k));
            acc.x = fmaf(a, nb[k].x, acc.x);
            acc.y = fmaf(a, nb[k].y, acc.y);
        }

        // stage cat = [embf_row, agg] into LDS
        *(float2*)&catbuf[r][2 * lane]       = ef;
        *(float2*)&catbuf[r][EMB + 2 * lane] = acc;
    }
    __syncthreads();

    // ---------------- Phase B: gate GEMM + blend ----------------
    const int p  = tid & 63;
    const int g  = tid >> 6;       // == wave (divergence is wave-uniform)
    const int c0 = 2 * p, c1 = c0 + 1;
    const int jbase = g * 64;

    float acc0[FB], acc1[FB];
#pragma unroll
    for (int r = 0; r < FB; ++r) { acc0[r] = 0.f; acc1[r] = 0.f; }

    const float* W0 = W + (size_t)c0 * (2 * EMB) + jbase;
    const float* W1 = W + (size_t)c1 * (2 * EMB) + jbase;

#pragma unroll 4
    for (int j = 0; j < 64; j += 4) {
        const float4 w0 = *(const float4*)(W0 + j);
        const float4 w1 = *(const float4*)(W1 + j);
#pragma unroll
        for (int r = 0; r < FB; ++r) {
            const float4 cv = *(const float4*)&catbuf[r][jbase + j];  // broadcast
            acc0[r] += cv.x * w0.x + cv.y * w0.y + cv.z * w0.z + cv.w * w0.w;
            acc1[r] += cv.x * w1.x + cv.y * w1.y + cv.z * w1.z + cv.w * w1.w;
        }
    }

    // combine the 4 j-quarter partials via LDS (wave-serialized, cheap)
    if (g == 3) {
#pragma unroll
        for (int r = 0; r < FB; ++r) { pbuf[r][c0] = acc0[r]; pbuf[r][c1] = acc1[r]; }
    }
    __syncthreads();
    if (g == 2) {
#pragma unroll
        for (int r = 0; r < FB; ++r) { pbuf[r][c0] += acc0[r]; pbuf[r][c1] += acc1[r]; }
    }
    __syncthreads();
    if (g == 1) {
#pragma unroll
        for (int r = 0; r < FB; ++r) { pbuf[r][c0] += acc0[r]; pbuf[r][c1] += acc1[r]; }
    }
    __syncthreads();
    if (g == 0) {
        const float2 bv = *(const float2*)(bias + c0);
#pragma unroll
        for (int r = 0; r < FB; ++r) {
            const float t0 = acc0[r] + pbuf[r][c0] + bv.x;
            const float t1 = acc1[r] + pbuf[r][c1] + bv.y;
            const float g0 = 1.f / (1.f + __expf(-t0));
            const float g1 = 1.f / (1.f + __expf(-t1));
            const float e0 = catbuf[r][c0],       e1 = catbuf[r][c1];
            const float a0 = catbuf[r][EMB + c0], a1 = catbuf[r][EMB + c1];
            float2 o;
            o.x = g0 * e0 + (1.f - g0) * a0;
            o.y = g1 * e1 + (1.f - g1) * a1;
            *(float2*)(out + (size_t)(fbase + r) * EMB + c0) = o;
        }
    }
}

extern "C" void kernel_launch(void* const* d_in, const int* in_sizes, int n_in,
                              void* d_out, int out_size, void* d_ws, size_t ws_size,
                              hipStream_t stream) {
    const int*   adj  = (const int*)  d_in[0];  // adjacency_fi [F,K] int32
    const float* embi = (const float*)d_in[1];  // embedding_i [N,E]
    const float* embf = (const float*)d_in[2];  // embedding_f_weight [F,E]
    const float* u    = (const float*)d_in[3];  // u [E,1]
    const float* W    = (const float*)d_in[4];  // W_weight [E,2E]
    const float* bias = (const float*)d_in[5];  // W_bias [E]
    float* outp = (float*)d_out;
    float* y    = (float*)d_ws;                 // N_NODE floats (400 KB scratch)

    node_scores<<<3125, 256, 0, stream>>>(embi, u, y);
    fused_gnn<<<F_TOTAL / FB, 256, 0, stream>>>(adj, embi, embf, y, W, bias, outp);
}